// Round 1
// baseline (9708.904 us; speedup 1.0000x reference)
//
#include <hip/hip_runtime.h>
#include <math.h>

#define BB 4
#define CC 256
#define HH_ 96
#define WW_ 160
#define HW (HH_*WW_)
#define MD 3
#define KK 49
#define FF 64
#define H2 192
#define W2 320
#define HO 768
#define WO 1280

// ---------------- L2 normalize along C (both tensors in one launch) ----------
__global__ void l2norm_kernel(const float* __restrict__ x1, const float* __restrict__ x2,
                              float* __restrict__ o1, float* __restrict__ o2) {
    int idx = blockIdx.x * blockDim.x + threadIdx.x;
    int total = 2 * BB * HW;
    if (idx >= total) return;
    int which = idx / (BB * HW);
    int p = idx - which * (BB * HW);
    int b = p / HW;
    int pix = p - b * HW;
    const float* x = which ? x2 : x1;
    float* o = which ? o2 : o1;
    const float* base = x + (size_t)b * CC * HW + pix;
    float s = 0.f;
    for (int c = 0; c < CC; ++c) { float v = base[(size_t)c * HW]; s += v * v; }
    float n = fmaxf(sqrtf(s), 1e-12f);
    float inv = 1.f / n;
    float* ob = o + (size_t)b * CC * HW + pix;
    for (int c = 0; c < CC; ++c) ob[(size_t)c * HW] = base[(size_t)c * HW] * inv;
}

// ---------------- bilateral correlation -------------------------------------
__global__ void corr_kernel(const float* __restrict__ x1n, const float* __restrict__ x2n,
                            float* __restrict__ out) {
    int idx = blockIdx.x * blockDim.x + threadIdx.x;
    int total = BB * KK * HW;
    if (idx >= total) return;
    int x = idx % WW_;
    int y = (idx / WW_) % HH_;
    int k = (idx / HW) % KK;
    int b = idx / (KK * HW);
    int dy = k / 7 - MD;
    int dx = k % 7 - MD;
    int ay = y - dy, ax = x - dx;
    int by = y + dy, bx = x + dx;
    float acc = 0.f;
    if (ay >= 0 && ay < HH_ && ax >= 0 && ax < WW_ &&
        by >= 0 && by < HH_ && bx >= 0 && bx < WW_) {
        const float* pa = x1n + (size_t)b * CC * HW + ay * WW_ + ax;
        const float* pb = x2n + (size_t)b * CC * HW + by * WW_ + bx;
        for (int c = 0; c < CC; ++c)
            acc += pa[(size_t)c * HW] * pb[(size_t)c * HW];
    }
    out[idx] = acc;
}

// ---------------- layernorm over channels -----------------------------------
__global__ void ln_kernel(const float* __restrict__ xt, const float* __restrict__ g,
                          const float* __restrict__ bln, float* __restrict__ out) {
    int idx = blockIdx.x * blockDim.x + threadIdx.x;
    int total = BB * HW;
    if (idx >= total) return;
    int b = idx / HW;
    int pix = idx - b * HW;
    const float* base = xt + (size_t)b * CC * HW + pix;
    float s = 0.f, s2 = 0.f;
    for (int c = 0; c < CC; ++c) { float v = base[(size_t)c * HW]; s += v; s2 += v * v; }
    float m = s / CC;
    float var = fmaxf(s2 / CC - m * m, 0.f);
    float inv = rsqrtf(var + 1e-5f);
    float* ob = out + (size_t)b * CC * HW + pix;
    for (int c = 0; c < CC; ++c)
        ob[(size_t)c * HW] = (base[(size_t)c * HW] - m) * inv * g[c] + bln[c];
}

// ---------------- generic direct 3x3 conv (optional concat, residual, lrelu) -
__global__ void conv3x3_kernel(const float* __restrict__ in1, int C1,
                               const float* __restrict__ in2, int C2,
                               const float* __restrict__ w, const float* __restrict__ bias,
                               const float* __restrict__ res,
                               float* __restrict__ out,
                               int Cout, int Hh, int Ww, float slope, int do_act) {
    int idx = blockIdx.x * blockDim.x + threadIdx.x;
    int total = BB * Cout * Hh * Ww;
    if (idx >= total) return;
    int x = idx % Ww;
    int y = (idx / Ww) % Hh;
    int co = (idx / (Ww * Hh)) % Cout;
    int b = idx / (Ww * Hh * Cout);
    int Ct = C1 + C2;
    float acc = bias[co];
    const float* wbase = w + (size_t)co * Ct * 9;
    for (int ci = 0; ci < C1; ++ci) {
        const float* ib = in1 + (size_t)(b * C1 + ci) * Hh * Ww;
        const float* wp = wbase + ci * 9;
#pragma unroll
        for (int ky = 0; ky < 3; ++ky) {
            int yy = y + ky - 1;
            if ((unsigned)yy >= (unsigned)Hh) continue;
#pragma unroll
            for (int kx = 0; kx < 3; ++kx) {
                int xx = x + kx - 1;
                if ((unsigned)xx >= (unsigned)Ww) continue;
                acc += ib[yy * Ww + xx] * wp[ky * 3 + kx];
            }
        }
    }
    if (in2) {
        for (int ci = 0; ci < C2; ++ci) {
            const float* ib = in2 + (size_t)(b * C2 + ci) * Hh * Ww;
            const float* wp = wbase + (C1 + ci) * 9;
#pragma unroll
            for (int ky = 0; ky < 3; ++ky) {
                int yy = y + ky - 1;
                if ((unsigned)yy >= (unsigned)Hh) continue;
#pragma unroll
                for (int kx = 0; kx < 3; ++kx) {
                    int xx = x + kx - 1;
                    if ((unsigned)xx >= (unsigned)Ww) continue;
                    acc += ib[yy * Ww + xx] * wp[ky * 3 + kx];
                }
            }
        }
    }
    if (res) acc += res[idx];
    if (do_act) acc = acc >= 0.f ? acc : slope * acc;
    out[idx] = acc;
}

// ---------------- transposed conv (stride 2) --------------------------------
__global__ void deconv_kernel(const float* __restrict__ in, const float* __restrict__ wdec,
                              const float* __restrict__ bdec, float* __restrict__ out) {
    int idx = blockIdx.x * blockDim.x + threadIdx.x;
    int total = BB * FF * H2 * W2;
    if (idx >= total) return;
    int ox = idx % W2;
    int oy = (idx / W2) % H2;
    int co = (idx / (W2 * H2)) % FF;
    int b = idx / (W2 * H2 * FF);
    float acc = bdec[co];
#pragma unroll
    for (int ky = 0; ky < 3; ++ky) {
        int t = oy + ky - 1;
        if (t & 1) continue;            // (t<0 -> t==-1 is odd, also skipped)
        int iy = t >> 1;
        if (iy < 0 || iy >= HH_) continue;
#pragma unroll
        for (int kx = 0; kx < 3; ++kx) {
            int s = ox + kx - 1;
            if (s & 1) continue;
            int ix = s >> 1;
            if (ix < 0 || ix >= WW_) continue;
            const float* ib = in + (size_t)b * FF * HW + iy * WW_ + ix;
            const float* wp = wdec + (size_t)co * 9 + (2 - ky) * 3 + (2 - kx);
            for (int ci = 0; ci < FF; ++ci)
                acc += ib[(size_t)ci * HW] * wp[(size_t)ci * FF * 9];
        }
    }
    out[idx] = acc;
}

// ---------------- bilinear x4 upsample, scale *4 ----------------------------
__global__ void resize_kernel(const float* __restrict__ flow, float* __restrict__ out) {
    int idx = blockIdx.x * blockDim.x + threadIdx.x;
    int total = BB * 2 * HO * WO;
    if (idx >= total) return;
    int ox = idx % WO;
    int oy = (idx / WO) % HO;
    int c = (idx / (WO * HO)) % 2;
    int b = idx / (WO * HO * 2);
    float sy = (oy + 0.5f) * 0.25f - 0.5f;
    float sx = (ox + 0.5f) * 0.25f - 0.5f;
    int y0 = (int)floorf(sy);
    int x0 = (int)floorf(sx);
    float fy = sy - y0;
    float fx = sx - x0;
    int y0c = min(max(y0, 0), H2 - 1);
    int y1c = min(max(y0 + 1, 0), H2 - 1);
    int x0c = min(max(x0, 0), W2 - 1);
    int x1c = min(max(x0 + 1, 0), W2 - 1);
    const float* fb = flow + (size_t)(b * 2 + c) * H2 * W2;
    float v00 = fb[y0c * W2 + x0c];
    float v01 = fb[y0c * W2 + x1c];
    float v10 = fb[y1c * W2 + x0c];
    float v11 = fb[y1c * W2 + x1c];
    float v = (1.f - fy) * ((1.f - fx) * v00 + fx * v01)
            + fy * ((1.f - fx) * v10 + fx * v11);
    out[idx] = v * 4.0f;
}

extern "C" void kernel_launch(void* const* d_in, const int* in_sizes, int n_in,
                              void* d_out, int out_size, void* d_ws, size_t ws_size,
                              hipStream_t stream) {
    const float* x1  = (const float*)d_in[0];
    const float* x2  = (const float*)d_in[1];
    const float* xt  = (const float*)d_in[2];
    const float* gln = (const float*)d_in[3];
    const float* bln = (const float*)d_in[4];
    const float* w0  = (const float*)d_in[5];
    const float* b0  = (const float*)d_in[6];
    const float* wr1 = (const float*)d_in[7];
    const float* br1 = (const float*)d_in[8];
    const float* wr2 = (const float*)d_in[9];
    const float* br2 = (const float*)d_in[10];
    const float* w2  = (const float*)d_in[11];
    const float* b2  = (const float*)d_in[12];
    const float* w3  = (const float*)d_in[13];
    const float* b3  = (const float*)d_in[14];
    const float* wdec= (const float*)d_in[15];
    const float* bdec= (const float*)d_in[16];
    const float* wf  = (const float*)d_in[17];
    const float* bf  = (const float*)d_in[18];
    float* out = (float*)d_out;

    float* ws = (float*)d_ws;
    // workspace layout (floats)
    const size_t X1N  = 0;            // 15,728,640  (later: LN output)
    const size_t X2N  = 15728640;     // 15,728,640  (later: deconv output)
    const size_t CORR = 31457280;     //  3,010,560  (later: flow)
    const size_t Y0   = 34467840;     //  3,932,160
    const size_t R1   = 38400000;     //  3,932,160
    const size_t YRES = 42332160;     //  3,932,160
    float* x1n  = ws + X1N;
    float* x2n  = ws + X2N;
    float* corr = ws + CORR;
    float* lnb  = ws + X1N;   // reuse after corr
    float* y0   = ws + Y0;
    float* r1   = ws + R1;
    float* yres = ws + YRES;
    float* dec  = ws + X2N;   // reuse after corr
    float* flow = ws + CORR;  // reuse after conv0

    const int T = 256;
    // 1. l2 normalize
    {
        int total = 2 * BB * HW;
        l2norm_kernel<<<(total + T - 1) / T, T, 0, stream>>>(x1, x2, x1n, x2n);
    }
    // 2. correlation
    {
        int total = BB * KK * HW;
        corr_kernel<<<(total + T - 1) / T, T, 0, stream>>>(x1n, x2n, corr);
    }
    // 3. layernorm (into x1n region)
    {
        int total = BB * HW;
        ln_kernel<<<(total + T - 1) / T, T, 0, stream>>>(xt, gln, bln, lnb);
    }
    // 4. conv0: concat(ln, corr) 305 -> 64, no act
    {
        int total = BB * FF * HW;
        conv3x3_kernel<<<(total + T - 1) / T, T, 0, stream>>>(
            lnb, CC, corr, KK, w0, b0, nullptr, y0, FF, HH_, WW_, 0.f, 0);
    }
    // 5. r1 = lrelu(conv(y0, wr1), 0.1)
    {
        int total = BB * FF * HW;
        conv3x3_kernel<<<(total + T - 1) / T, T, 0, stream>>>(
            y0, FF, nullptr, 0, wr1, br1, nullptr, r1, FF, HH_, WW_, 0.1f, 1);
    }
    // 6. yres = lrelu(conv(r1, wr2) + y0, 0.1)
    {
        int total = BB * FF * HW;
        conv3x3_kernel<<<(total + T - 1) / T, T, 0, stream>>>(
            r1, FF, nullptr, 0, wr2, br2, y0, yres, FF, HH_, WW_, 0.1f, 1);
    }
    // 7. y2 = lrelu(conv(yres, w2), 0.2)  -> r1 buffer
    {
        int total = BB * FF * HW;
        conv3x3_kernel<<<(total + T - 1) / T, T, 0, stream>>>(
            yres, FF, nullptr, 0, w2, b2, nullptr, r1, FF, HH_, WW_, 0.2f, 1);
    }
    // 8. y3 = lrelu(conv(y2, w3), 0.2)  -> y0 buffer
    {
        int total = BB * FF * HW;
        conv3x3_kernel<<<(total + T - 1) / T, T, 0, stream>>>(
            r1, FF, nullptr, 0, w3, b3, nullptr, y0, FF, HH_, WW_, 0.2f, 1);
    }
    // 9. deconv y3 -> dec (192x320)
    {
        int total = BB * FF * H2 * W2;
        deconv_kernel<<<(total + T - 1) / T, T, 0, stream>>>(y0, wdec, bdec, dec);
    }
    // 10. flow = conv(dec, wf) 64 -> 2 (192x320)
    {
        int total = BB * 2 * H2 * W2;
        conv3x3_kernel<<<(total + T - 1) / T, T, 0, stream>>>(
            dec, FF, nullptr, 0, wf, bf, nullptr, flow, 2, H2, W2, 0.f, 0);
    }
    // 11. bilinear x4 upsample * 4.0
    {
        int total = BB * 2 * HO * WO;
        resize_kernel<<<(total + T - 1) / T, T, 0, stream>>>(flow, out);
    }
    (void)in_sizes; (void)n_in; (void)out_size; (void)ws_size; (void)n_in; (void)bf;
}

// Round 2
// 915.812 us; speedup vs baseline: 10.6014x; 10.6014x over previous
//
#include <hip/hip_runtime.h>
#include <math.h>

#define HH_ 96
#define WW_ 160
#define HW 15360          // 96*160
#define NPIX 61440        // 4*HW
#define CC 256
#define C0 320            // padded conv0 Cin
#define FF 64
#define H2 192
#define W2 320
#define OHW 61440         // 192*320
#define HO 768
#define WO 1280

typedef __attribute__((ext_vector_type(8))) short short8;
typedef __attribute__((ext_vector_type(4))) float f32x4;

__device__ __forceinline__ float bf2f(ushort u) {
    union { unsigned int i; float f; } v; v.i = ((unsigned int)u) << 16; return v.f;
}
__device__ __forceinline__ ushort f2bf(float f) {
    union { float f; unsigned int i; } v; v.f = f;
    unsigned int u = v.i;
    return (ushort)((u + 0x7FFFu + ((u >> 16) & 1u)) >> 16);
}

// ------------------------------------------------------------------ stats ---
__global__ void stats_kernel(const float* __restrict__ x1, const float* __restrict__ x2,
                             const float* __restrict__ xt,
                             float* __restrict__ inv1, float* __restrict__ inv2,
                             float* __restrict__ meanb, float* __restrict__ rstdb) {
    int p = blockIdx.x * blockDim.x + threadIdx.x;
    if (p >= NPIX) return;
    int b = p / HW, rem = p % HW;
    size_t base = (size_t)b * CC * HW + rem;
    float s1 = 0.f, s2 = 0.f, sm = 0.f, sq = 0.f;
    for (int c = 0; c < CC; ++c) {
        float v1 = x1[base + (size_t)c * HW];
        float v2 = x2[base + (size_t)c * HW];
        float v3 = xt[base + (size_t)c * HW];
        s1 += v1 * v1; s2 += v2 * v2; sm += v3; sq += v3 * v3;
    }
    inv1[p] = 1.f / fmaxf(sqrtf(s1), 1e-12f);
    inv2[p] = 1.f / fmaxf(sqrtf(s2), 1e-12f);
    float m = sm / CC;
    float var = fmaxf(sq / CC - m * m, 0.f);
    meanb[p] = m;
    rstdb[p] = rsqrtf(var + 1e-5f);
}

// ----------------------------------------------------- NCHW f32 -> NHWC bf16 -
__global__ void pack_x_kernel(const float* __restrict__ in, ushort* __restrict__ out) {
    __shared__ float tile[64][68];
    int t = threadIdx.x;
    int pxt = blockIdx.x, ct = blockIdx.y, b = blockIdx.z;
    const float* src = in + ((size_t)b * CC + ct * 64) * HW + pxt * 64;
    for (int i = 0; i < 16; ++i) {
        int c_l = i * 4 + (t >> 6);
        int px_l = t & 63;
        tile[px_l][c_l] = src[(size_t)c_l * HW + px_l];
    }
    __syncthreads();
    int px_l = t >> 2, cg = t & 3;
    size_t ob = ((size_t)b * HW + pxt * 64 + px_l) * CC + ct * 64 + cg * 16;
    short8 v0, v1;
    for (int j = 0; j < 8; ++j) {
        v0[j] = (short)f2bf(tile[px_l][cg * 16 + j]);
        v1[j] = (short)f2bf(tile[px_l][cg * 16 + 8 + j]);
    }
    *(short8*)(out + ob) = v0;
    *(short8*)(out + ob + 8) = v1;
}

// ------------------------------------------- LN + pack into X0 (hi/lo bf16) -
__global__ void pack_ln_kernel(const float* __restrict__ xt,
                               const float* __restrict__ gam, const float* __restrict__ bet,
                               const float* __restrict__ meanb, const float* __restrict__ rstdb,
                               ushort* __restrict__ Xhi, ushort* __restrict__ Xlo) {
    __shared__ float tile[64][68];
    int t = threadIdx.x;
    int pxt = blockIdx.x, ct = blockIdx.y, b = blockIdx.z;
    const float* src = xt + ((size_t)b * CC + ct * 64) * HW + pxt * 64;
    for (int i = 0; i < 16; ++i) {
        int c_l = i * 4 + (t >> 6);
        int px_l = t & 63;
        tile[px_l][c_l] = src[(size_t)c_l * HW + px_l];
    }
    __syncthreads();
    int px_l = t >> 2, cg = t & 3;
    int p = b * HW + pxt * 64 + px_l;
    float m = meanb[p], rs = rstdb[p];
    size_t ob = (size_t)p * C0 + ct * 64 + cg * 16;
    short8 h0, h1, l0, l1;
    for (int j = 0; j < 8; ++j) {
        int c = ct * 64 + cg * 16 + j;
        float f = (tile[px_l][cg * 16 + j] - m) * rs * gam[c] + bet[c];
        ushort h = f2bf(f);
        h0[j] = (short)h; l0[j] = (short)f2bf(f - bf2f(h));
        c = ct * 64 + cg * 16 + 8 + j;
        f = (tile[px_l][cg * 16 + 8 + j] - m) * rs * gam[c] + bet[c];
        h = f2bf(f);
        h1[j] = (short)h; l1[j] = (short)f2bf(f - bf2f(h));
    }
    *(short8*)(Xhi + ob) = h0; *(short8*)(Xhi + ob + 8) = h1;
    *(short8*)(Xlo + ob) = l0; *(short8*)(Xlo + ob + 8) = l1;
}

// ---------------------------------------------------------------- corr ------
__global__ void corr_kernel(const ushort* __restrict__ x1c, const ushort* __restrict__ x2c,
                            const float* __restrict__ inv1, const float* __restrict__ inv2,
                            ushort* __restrict__ Xhi, ushort* __restrict__ Xlo) {
    int wid = (blockIdx.x * blockDim.x + threadIdx.x) >> 6;
    int lane = threadIdx.x & 63;
    if (wid >= NPIX) return;
    int b = wid / HW, rem = wid % HW, y = rem / WW_, x = rem % WW_;
    float keep = 0.f;
    for (int d = 0; d < 49; ++d) {
        int dy = d / 7 - 3, dx = d % 7 - 3;
        int ay = y - dy, ax = x - dx, by = y + dy, bx = x + dx;
        float s = 0.f;
        if ((unsigned)ay < 96u && (unsigned)ax < 160u &&
            (unsigned)by < 96u && (unsigned)bx < 160u) {
            int pa = b * HW + ay * WW_ + ax;
            int pb = b * HW + by * WW_ + bx;
            unsigned long long a8 = *(const unsigned long long*)(x1c + (size_t)pa * CC + lane * 4);
            unsigned long long b8 = *(const unsigned long long*)(x2c + (size_t)pb * CC + lane * 4);
            for (int j = 0; j < 4; ++j)
                s += bf2f((ushort)(a8 >> (16 * j))) * bf2f((ushort)(b8 >> (16 * j)));
            for (int off = 32; off; off >>= 1) s += __shfl_xor(s, off);
            s *= inv1[pa] * inv2[pb];
        }
        if (lane == d) keep = s;
    }
    float v = (lane < 49) ? keep : 0.f;
    ushort h = f2bf(v);
    size_t o = (size_t)wid * C0 + 256 + lane;
    Xhi[o] = h;
    Xlo[o] = f2bf(v - bf2f(h));
}

// ------------------------------------------------------------ weight pack ---
__global__ void pack_w_kernel(const float* __restrict__ w, int CinReal, int KC, int isDeconv,
                              ushort* __restrict__ whi, ushort* __restrict__ wlo) {
    int gid = blockIdx.x * blockDim.x + threadIdx.x;
    int total = 9 * KC * 4 * 64;
    if (gid >= total) return;
    int lane = gid & 63;
    int nt = (gid >> 6) & 3;
    int kc = (gid >> 8) % KC;
    int slot = (gid >> 8) / KC;
    int co = nt * 16 + (lane & 15);
    int ky = slot / 3, kx = slot % 3;
    for (int j = 0; j < 8; ++j) {
        int ci = kc * 32 + (lane >> 4) * 8 + j;
        float v = 0.f;
        if (ci < CinReal) {
            if (isDeconv) v = w[((size_t)(ci * 64 + co) * 3 + (2 - ky)) * 3 + (2 - kx)];
            else          v = w[((size_t)(co * CinReal + ci) * 3 + ky) * 3 + kx];
        }
        ushort h = f2bf(v);
        whi[(size_t)gid * 8 + j] = h;
        wlo[(size_t)gid * 8 + j] = f2bf(v - bf2f(h));
    }
}

// -------------------------------------------------------- MFMA conv core ----
struct TapList { int dy[9]; int dx[9]; int slot[9]; int n; };

__global__ __launch_bounds__(256) void conv_mfma_kernel(
    const ushort* __restrict__ Ahi, const ushort* __restrict__ Alo,
    int CIN, int KC,
    const ushort* __restrict__ Whi, const ushort* __restrict__ Wlo,
    const float* __restrict__ bias,
    TapList taps,
    ushort* __restrict__ Ohi, ushort* __restrict__ Olo,
    const ushort* __restrict__ Rhi, const ushort* __restrict__ Rlo,
    float slope, int act, int hasres,
    int Ho, int Wo, int sy, int sx, int py, int px) {
    const int lane = threadIdx.x & 63;
    const int wave = threadIdx.x >> 6;
    const int kg = lane >> 4;
    const int tileBase = (blockIdx.x * 4 + wave) * 32;
    const short8 zero8 = {0, 0, 0, 0, 0, 0, 0, 0};

    int pm0 = tileBase + (lane & 15);
    int pm1 = pm0 + 16;
    int b0 = pm0 / HW, r0 = pm0 % HW, y0 = r0 / WW_, x0 = r0 % WW_;
    int b1 = pm1 / HW, r1 = pm1 % HW, y1 = r1 / WW_, x1 = r1 % WW_;

    f32x4 acc[2][4];
    for (int s = 0; s < 2; ++s)
        for (int nt = 0; nt < 4; ++nt)
            acc[s][nt] = (f32x4){0.f, 0.f, 0.f, 0.f};

    for (int t = 0; t < taps.n; ++t) {
        int dy = taps.dy[t], dx = taps.dx[t];
        int yy0 = y0 + dy, xx0 = x0 + dx, yy1 = y1 + dy, xx1 = x1 + dx;
        bool v0 = (unsigned)yy0 < 96u && (unsigned)xx0 < 160u;
        bool v1 = (unsigned)yy1 < 96u && (unsigned)xx1 < 160u;
        int yy0c = min(max(yy0, 0), 95), xx0c = min(max(xx0, 0), 159);
        int yy1c = min(max(yy1, 0), 95), xx1c = min(max(xx1, 0), 159);
        size_t a0 = ((size_t)b0 * HW + yy0c * WW_ + xx0c) * (size_t)CIN + kg * 8;
        size_t a1 = ((size_t)b1 * HW + yy1c * WW_ + xx1c) * (size_t)CIN + kg * 8;
        const ushort* wh_t = Whi + (size_t)taps.slot[t] * KC * 4 * 64 * 8;
        const ushort* wl_t = Wlo + (size_t)taps.slot[t] * KC * 4 * 64 * 8;
        for (int kc = 0; kc < KC; ++kc) {
            short8 ah0 = *(const short8*)(Ahi + a0 + kc * 32);
            short8 al0 = *(const short8*)(Alo + a0 + kc * 32);
            short8 ah1 = *(const short8*)(Ahi + a1 + kc * 32);
            short8 al1 = *(const short8*)(Alo + a1 + kc * 32);
            if (!v0) { ah0 = zero8; al0 = zero8; }
            if (!v1) { ah1 = zero8; al1 = zero8; }
#pragma unroll
            for (int nt = 0; nt < 4; ++nt) {
                size_t wo = (((size_t)kc * 4 + nt) * 64 + lane) * 8;
                short8 bh = *(const short8*)(wh_t + wo);
                short8 bl = *(const short8*)(wl_t + wo);
                acc[0][nt] = __builtin_amdgcn_mfma_f32_16x16x32_bf16(ah0, bh, acc[0][nt], 0, 0, 0);
                acc[1][nt] = __builtin_amdgcn_mfma_f32_16x16x32_bf16(ah1, bh, acc[1][nt], 0, 0, 0);
                acc[0][nt] = __builtin_amdgcn_mfma_f32_16x16x32_bf16(al0, bh, acc[0][nt], 0, 0, 0);
                acc[1][nt] = __builtin_amdgcn_mfma_f32_16x16x32_bf16(al1, bh, acc[1][nt], 0, 0, 0);
                acc[0][nt] = __builtin_amdgcn_mfma_f32_16x16x32_bf16(ah0, bl, acc[0][nt], 0, 0, 0);
                acc[1][nt] = __builtin_amdgcn_mfma_f32_16x16x32_bf16(ah1, bl, acc[1][nt], 0, 0, 0);
            }
        }
    }

    for (int s = 0; s < 2; ++s) {
        for (int r = 0; r < 4; ++r) {
            int pr = tileBase + s * 16 + kg * 4 + r;
            int b2 = pr / HW, rr = pr % HW, y2 = rr / WW_, x2 = rr % WW_;
            size_t po = ((size_t)b2 * Ho + y2 * sy + py) * Wo + x2 * sx + px;
            for (int nt = 0; nt < 4; ++nt) {
                int co = nt * 16 + (lane & 15);
                float v = acc[s][nt][r] + bias[co];
                size_t oo = po * 64 + co;
                if (hasres) v += bf2f(Rhi[oo]) + bf2f(Rlo[oo]);
                if (act) v = v >= 0.f ? v : v * slope;
                ushort h = f2bf(v);
                Ohi[oo] = h;
                Olo[oo] = f2bf(v - bf2f(h));
            }
        }
    }
}

// ---------------------------------------------------------------- flow ------
__global__ __launch_bounds__(256) void flow_kernel(const ushort* __restrict__ dechi,
                                                   const ushort* __restrict__ declo,
                                                   const float* __restrict__ wf,
                                                   const float* __restrict__ bf2v,
                                                   float* __restrict__ flow) {
    __shared__ float wsm[1152];
    for (int i = threadIdx.x; i < 1152; i += 256) wsm[i] = wf[i];
    __syncthreads();
    int p = blockIdx.x * 256 + threadIdx.x;
    if (p >= 4 * OHW) return;
    int b = p / OHW, rem = p % OHW, oy = rem / W2, ox = rem % W2;
    float a0 = bf2v[0], a1 = bf2v[1];
    for (int ky = 0; ky < 3; ++ky) {
        int yy = oy + ky - 1;
        if ((unsigned)yy >= (unsigned)H2) continue;
        for (int kx = 0; kx < 3; ++kx) {
            int xx = ox + kx - 1;
            if ((unsigned)xx >= (unsigned)W2) continue;
            size_t base = ((size_t)b * OHW + yy * W2 + xx) * 64;
            int tap = ky * 3 + kx;
            for (int c4 = 0; c4 < 16; ++c4) {
                unsigned long long h8 = *(const unsigned long long*)(dechi + base + c4 * 4);
                unsigned long long l8 = *(const unsigned long long*)(declo + base + c4 * 4);
                for (int j = 0; j < 4; ++j) {
                    float f = bf2f((ushort)(h8 >> (16 * j))) + bf2f((ushort)(l8 >> (16 * j)));
                    int ci = c4 * 4 + j;
                    a0 += f * wsm[ci * 9 + tap];
                    a1 += f * wsm[(64 + ci) * 9 + tap];
                }
            }
        }
    }
    flow[(size_t)(b * 2 + 0) * OHW + rem] = a0;
    flow[(size_t)(b * 2 + 1) * OHW + rem] = a1;
}

// --------------------------------------------------------------- resize -----
__global__ void resize_kernel(const float* __restrict__ flow, float* __restrict__ out) {
    int idx = blockIdx.x * blockDim.x + threadIdx.x;
    int total = 4 * 2 * HO * WO;
    if (idx >= total) return;
    int ox = idx % WO;
    int oy = (idx / WO) % HO;
    int c = (idx / (WO * HO)) % 2;
    int b = idx / (WO * HO * 2);
    float sy = (oy + 0.5f) * 0.25f - 0.5f;
    float sx = (ox + 0.5f) * 0.25f - 0.5f;
    int y0 = (int)floorf(sy);
    int x0 = (int)floorf(sx);
    float fy = sy - y0;
    float fx = sx - x0;
    int y0c = min(max(y0, 0), H2 - 1);
    int y1c = min(max(y0 + 1, 0), H2 - 1);
    int x0c = min(max(x0, 0), W2 - 1);
    int x1c = min(max(x0 + 1, 0), W2 - 1);
    const float* fb = flow + (size_t)(b * 2 + c) * OHW;
    float v00 = fb[y0c * W2 + x0c];
    float v01 = fb[y0c * W2 + x1c];
    float v10 = fb[y1c * W2 + x0c];
    float v11 = fb[y1c * W2 + x1c];
    float v = (1.f - fy) * ((1.f - fx) * v00 + fx * v01)
            + fy * ((1.f - fx) * v10 + fx * v11);
    out[idx] = v * 4.0f;
}

// =================================================================== host ===
extern "C" void kernel_launch(void* const* d_in, const int* in_sizes, int n_in,
                              void* d_out, int out_size, void* d_ws, size_t ws_size,
                              hipStream_t stream) {
    const float* x1   = (const float*)d_in[0];
    const float* x2   = (const float*)d_in[1];
    const float* xt   = (const float*)d_in[2];
    const float* gln  = (const float*)d_in[3];
    const float* bln  = (const float*)d_in[4];
    const float* w0   = (const float*)d_in[5];
    const float* b0   = (const float*)d_in[6];
    const float* wr1  = (const float*)d_in[7];
    const float* br1  = (const float*)d_in[8];
    const float* wr2  = (const float*)d_in[9];
    const float* br2  = (const float*)d_in[10];
    const float* b2   = (const float*)d_in[12];
    const float* w2   = (const float*)d_in[11];
    const float* w3   = (const float*)d_in[13];
    const float* b3   = (const float*)d_in[14];
    const float* wdec = (const float*)d_in[15];
    const float* bdec = (const float*)d_in[16];
    const float* wf   = (const float*)d_in[17];
    const float* bfv  = (const float*)d_in[18];
    float* out = (float*)d_out;

    char* ws = (char*)d_ws;
    // ---- workspace byte offsets ----
    float*  inv1  = (float*)(ws + 0);
    float*  inv2  = (float*)(ws + 245760);
    float*  meanb = (float*)(ws + 491520);
    float*  rstdb = (float*)(ws + 737280);
    ushort* x1c   = (ushort*)(ws + 1048576);                 // 31,457,280 B
    ushort* x2c   = (ushort*)(ws + 1048576 + 31457280);
    ushort* X0hi  = (ushort*)(ws + 67108864);                // 39,321,600 B
    ushort* X0lo  = (ushort*)(ws + 106430464);
    // Y planes reuse x1c/x2c region after corr
    const size_t P = 7864320;
    ushort* y0hi = (ushort*)(ws + 1048576 + 0 * P);
    ushort* y0lo = (ushort*)(ws + 1048576 + 1 * P);
    ushort* t1hi = (ushort*)(ws + 1048576 + 2 * P);
    ushort* t1lo = (ushort*)(ws + 1048576 + 3 * P);
    ushort* t2hi = (ushort*)(ws + 1048576 + 4 * P);
    ushort* t2lo = (ushort*)(ws + 1048576 + 5 * P);
    // dec + flow reuse X0 region after conv0
    ushort* dechi = (ushort*)(ws + 67108864);                // 31,457,280
    ushort* declo = (ushort*)(ws + 98566144);
    float*  flowb = (float*)(ws + 130023424);                // 1,966,080
    // packed weights
    char* wp = ws + 146800640;
    ushort* W0hi  = (ushort*)(wp);             ushort* W0lo  = (ushort*)(wp + 368640);
    ushort* WR1hi = (ushort*)(wp + 737280);    ushort* WR1lo = (ushort*)(wp + 737280 + 73728);
    ushort* WR2hi = (ushort*)(wp + 884736);    ushort* WR2lo = (ushort*)(wp + 884736 + 73728);
    ushort* W2hi  = (ushort*)(wp + 1032192);   ushort* W2lo  = (ushort*)(wp + 1032192 + 73728);
    ushort* W3hi  = (ushort*)(wp + 1179648);   ushort* W3lo  = (ushort*)(wp + 1179648 + 73728);
    ushort* WDhi  = (ushort*)(wp + 1327104);   ushort* WDlo  = (ushort*)(wp + 1327104 + 73728);

    // ---- tap lists ----
    TapList T9; T9.n = 9;
    for (int ky = 0; ky < 3; ++ky)
        for (int kx = 0; kx < 3; ++kx) {
            int i = ky * 3 + kx;
            T9.dy[i] = ky - 1; T9.dx[i] = kx - 1; T9.slot[i] = i;
        }
    TapList D00; D00.n = 1; D00.dy[0] = 0; D00.dx[0] = 0; D00.slot[0] = 4;
    TapList D01; D01.n = 2;
    D01.dy[0] = 0; D01.dx[0] = 0; D01.slot[0] = 3;
    D01.dy[1] = 0; D01.dx[1] = 1; D01.slot[1] = 5;
    TapList D10; D10.n = 2;
    D10.dy[0] = 0; D10.dx[0] = 0; D10.slot[0] = 1;
    D10.dy[1] = 1; D10.dx[1] = 0; D10.slot[1] = 7;
    TapList D11; D11.n = 4;
    D11.dy[0] = 0; D11.dx[0] = 0; D11.slot[0] = 0;
    D11.dy[1] = 0; D11.dx[1] = 1; D11.slot[1] = 2;
    D11.dy[2] = 1; D11.dx[2] = 0; D11.slot[2] = 6;
    D11.dy[3] = 1; D11.dx[3] = 1; D11.slot[3] = 8;

    // ---- weight packing ----
    pack_w_kernel<<<90, 256, 0, stream>>>(w0, 305, 10, 0, W0hi, W0lo);
    pack_w_kernel<<<18, 256, 0, stream>>>(wr1, 64, 2, 0, WR1hi, WR1lo);
    pack_w_kernel<<<18, 256, 0, stream>>>(wr2, 64, 2, 0, WR2hi, WR2lo);
    pack_w_kernel<<<18, 256, 0, stream>>>(w2, 64, 2, 0, W2hi, W2lo);
    pack_w_kernel<<<18, 256, 0, stream>>>(w3, 64, 2, 0, W3hi, W3lo);
    pack_w_kernel<<<18, 256, 0, stream>>>(wdec, 64, 2, 1, WDhi, WDlo);

    // ---- stats + packs ----
    stats_kernel<<<240, 256, 0, stream>>>(x1, x2, xt, inv1, inv2, meanb, rstdb);
    pack_x_kernel<<<dim3(240, 4, 4), 256, 0, stream>>>(x1, x1c);
    pack_x_kernel<<<dim3(240, 4, 4), 256, 0, stream>>>(x2, x2c);
    pack_ln_kernel<<<dim3(240, 4, 4), 256, 0, stream>>>(xt, gln, bln, meanb, rstdb, X0hi, X0lo);
    corr_kernel<<<15360, 256, 0, stream>>>(x1c, x2c, inv1, inv2, X0hi, X0lo);

    // ---- conv chain ----
    // conv0: X0(320) -> y0, no act
    conv_mfma_kernel<<<480, 256, 0, stream>>>(X0hi, X0lo, C0, 10, W0hi, W0lo, b0, T9,
        y0hi, y0lo, nullptr, nullptr, 0.f, 0, 0, HH_, WW_, 1, 1, 0, 0);
    // r1 = lrelu(conv(y0, wr1), 0.1)
    conv_mfma_kernel<<<480, 256, 0, stream>>>(y0hi, y0lo, 64, 2, WR1hi, WR1lo, br1, T9,
        t1hi, t1lo, nullptr, nullptr, 0.1f, 1, 0, HH_, WW_, 1, 1, 0, 0);
    // yres = lrelu(conv(r1, wr2) + y0, 0.1)
    conv_mfma_kernel<<<480, 256, 0, stream>>>(t1hi, t1lo, 64, 2, WR2hi, WR2lo, br2, T9,
        t2hi, t2lo, y0hi, y0lo, 0.1f, 1, 1, HH_, WW_, 1, 1, 0, 0);
    // y2 = lrelu(conv(yres, w2), 0.2)
    conv_mfma_kernel<<<480, 256, 0, stream>>>(t2hi, t2lo, 64, 2, W2hi, W2lo, b2, T9,
        t1hi, t1lo, nullptr, nullptr, 0.2f, 1, 0, HH_, WW_, 1, 1, 0, 0);
    // y3 = lrelu(conv(y2, w3), 0.2)
    conv_mfma_kernel<<<480, 256, 0, stream>>>(t1hi, t1lo, 64, 2, W3hi, W3lo, b3, T9,
        t2hi, t2lo, nullptr, nullptr, 0.2f, 1, 0, HH_, WW_, 1, 1, 0, 0);
    // deconv: 4 parity classes t2 -> dec (192x320)
    conv_mfma_kernel<<<480, 256, 0, stream>>>(t2hi, t2lo, 64, 2, WDhi, WDlo, bdec, D00,
        dechi, declo, nullptr, nullptr, 0.f, 0, 0, H2, W2, 2, 2, 0, 0);
    conv_mfma_kernel<<<480, 256, 0, stream>>>(t2hi, t2lo, 64, 2, WDhi, WDlo, bdec, D01,
        dechi, declo, nullptr, nullptr, 0.f, 0, 0, H2, W2, 2, 2, 0, 1);
    conv_mfma_kernel<<<480, 256, 0, stream>>>(t2hi, t2lo, 64, 2, WDhi, WDlo, bdec, D10,
        dechi, declo, nullptr, nullptr, 0.f, 0, 0, H2, W2, 2, 2, 1, 0);
    conv_mfma_kernel<<<480, 256, 0, stream>>>(t2hi, t2lo, 64, 2, WDhi, WDlo, bdec, D11,
        dechi, declo, nullptr, nullptr, 0.f, 0, 0, H2, W2, 2, 2, 1, 1);

    // ---- flow + resize ----
    flow_kernel<<<960, 256, 0, stream>>>(dechi, declo, wf, bfv, flowb);
    resize_kernel<<<30720, 256, 0, stream>>>(flowb, out);

    (void)in_sizes; (void)n_in; (void)out_size; (void)ws_size;
}